// Round 19
// baseline (42.276 us; speedup 1.0000x reference)
//
#include <hip/hip_runtime.h>
#include <hip/hip_fp16.h>

#define DX 160
#define DY 192
#define DZ 160
#define PLANE (DY*DZ)
#define NVOX (DX*DY*DZ)

#define XC   10              // interior x slices per wave (R19: 20->10, 2x waves)
#define NXB  (DX/XC)         // 16
#define NS   (XC+4)          // 14
#define WPB  4               // waves per block (4 consecutive y, same seg)
#define NT   (WPB*64)        // 256 threads
#define NSEG 3               // z segments: zbase = 60*seg - 2, 60 outputs each
#define NTASK (DY*NSEG)      // 576 wave-tasks per x-tile
#define NBY  (NTASK/WPB)     // 144
#define NPART (NXB*NBY*WPB)  // 9216

__device__ __forceinline__ int iclamp(int v, int hi) {
    return v < 0 ? 0 : (v > hi ? hi : v);
}
__device__ __forceinline__ unsigned pk(float a, float b) {
    return __builtin_bit_cast(unsigned, __floats2half2_rn(a, b));
}
__device__ __forceinline__ __half2 h2(unsigned v) {
    return __builtin_bit_cast(__half2, v);
}
__device__ __forceinline__ float lo16(unsigned u) { return __low2float(h2(u)); }
__device__ __forceinline__ float hi16(unsigned u) { return __high2float(h2(u)); }

// ---------------------------------------------------------------------------
// Wave-autonomous fused LCC, max-occupancy edition.
// R18 fit the 64-VGPR budget (spill gone) but was grid-capped at 18 waves/CU
// (56%) and ran ~33us against 7.6us of pure VALU -- per-wave dependency
// chains at ~4.5 waves/SIMD leave the issue slots empty. Nothing in this
// structure (LDS=0, VGPR=64) blocks the full 32 waves/CU: this round doubles
// the wave count via XC=10 -> 2304 blocks (9216 waves, 36/CU requested, HW
// caps at 32). +17% halo work, traded for ~2x resident parallelism.
// Structure unchanged from R18 (proven correct): lane owns one z; wave = 64
// consecutive z with 2-lane halos; y-box direct from global (L1-served);
// z-box via 4 shuffles x 3 fp16 words; x-box register running window.
// ---------------------------------------------------------------------------
__global__ __launch_bounds__(NT) void lcc_fused(const float* __restrict__ F,
                                                const float* __restrict__ M,
                                                float* __restrict__ partials) {
    const int tid  = threadIdx.x;
    const int lane = tid & 63;
    const int wid  = tid >> 6;
    const int task = blockIdx.y * WPB + wid;   // seg-major: 4 consecutive y/block
    const int seg  = task / DY;
    const int y    = task % DY;
    const int x0   = blockIdx.x * XC;
    const int z    = seg * 60 - 2 + lane;      // may be <0 or >=DZ (halo lanes)
    const int zl   = iclamp(z, DZ - 1);
    const float valid = (lane >= 2 && lane <= 61 && z < DZ) ? 1.f : 0.f;

    int rowoff[5];
    #pragma unroll
    for (int k = 0; k < 5; ++k)
        rowoff[k] = iclamp(y + k - 2, DY - 1) * DZ + zl;

    // x running-window state (scalar per lane)
    float s0 = 0.f, s1 = 0.f, s2 = 0.f, s3 = 0.f, s4 = 0.f;
    unsigned hA[4], hB[4], hC[4];   // fp16x2 history: (S0,S1),(S2,S3),(S4,-)
    #pragma unroll
    for (int a = 0; a < 4; ++a) { hA[a] = 0u; hB[a] = 0u; hC[a] = 0u; }
    float acc = 0.f;

    for (int i = 0; i < NS; ++i) {
        const int xx = iclamp(x0 + i - 2, DX - 1);
        const float* fp = F + (size_t)xx * PLANE;
        const float* mp = M + (size_t)xx * PLANE;

        // ---- y-box: 5 clamped rows straight from global (f32 exact) ----
        float q0 = 0.f, q1 = 0.f, q2 = 0.f, q3 = 0.f, q4 = 0.f;
        #pragma unroll
        for (int r = 0; r < 5; ++r) {
            const float fv = fp[rowoff[r]];
            const float mv = mp[rowoff[r]];
            q0 += fv; q1 += mv;
            q2 = fmaf(fv, mv, q2);
            q3 = fmaf(fv, fv, q3);
            q4 = fmaf(mv, mv, q4);
        }

        // ---- z-box via wave shuffles (taps z-2..z+2 in lanes l-2..l+2) ----
        const unsigned P01 = pk(q0, q1);
        const unsigned P23 = pk(q2, q3);
        const unsigned P4  = pk(q4, q4);
        const __half2 t01 = __hadd2(
            __hadd2(h2(__shfl_up(P01, 1, 64)), h2(__shfl_up(P01, 2, 64))),
            __hadd2(h2(__shfl_down(P01, 1, 64)), h2(__shfl_down(P01, 2, 64))));
        const __half2 t23 = __hadd2(
            __hadd2(h2(__shfl_up(P23, 1, 64)), h2(__shfl_up(P23, 2, 64))),
            __hadd2(h2(__shfl_down(P23, 1, 64)), h2(__shfl_down(P23, 2, 64))));
        const __half2 t4 = __hadd2(
            __hadd2(h2(__shfl_up(P4, 1, 64)), h2(__shfl_up(P4, 2, 64))),
            __hadd2(h2(__shfl_down(P4, 1, 64)), h2(__shfl_down(P4, 2, 64))));
        const float S0 = q0 + __low2float(t01);
        const float S1 = q1 + __high2float(t01);
        const float S2 = q2 + __low2float(t23);
        const float S3 = q3 + __high2float(t23);
        const float S4 = q4 + __low2float(t4);

        // ---- x running window + LCC ----
        s0 += S0; s1 += S1; s2 += S2; s3 += S3; s4 += S4;
        if (i >= 4) {
            const float inv = 1.0f / 125.0f;
            const float cross = s2 - s0 * s1 * inv;
            const float fvar  = s3 - s0 * s0 * inv;
            const float mvar  = s4 - s1 * s1 * inv;
            acc += valid * (cross * cross / (fvar * mvar + 0.1f));
            s0 -= lo16(hA[0]); s1 -= hi16(hA[0]);
            s2 -= lo16(hB[0]); s3 -= hi16(hB[0]);
            s4 -= lo16(hC[0]);
        }
        hA[0] = hA[1]; hA[1] = hA[2]; hA[2] = hA[3]; hA[3] = pk(S0, S1);
        hB[0] = hB[1]; hB[1] = hB[2]; hB[2] = hB[3]; hB[3] = pk(S2, S3);
        hC[0] = hC[1]; hC[1] = hC[2]; hC[2] = hC[3]; hC[3] = pk(S4, 0.f);
    }

    // ---- wave reduction; one partial per wave; no LDS, no barrier ----
    #pragma unroll
    for (int off = 32; off > 0; off >>= 1) acc += __shfl_down(acc, off, 64);
    if (lane == 0)
        partials[(blockIdx.y * NXB + blockIdx.x) * WPB + wid] = acc;
}

// ---------------------------------------------------------------------------
// Final deterministic reduction, writes -sum.
// ---------------------------------------------------------------------------
__global__ __launch_bounds__(256) void lcc_finalize(const float* __restrict__ partials,
                                                    int n, float* __restrict__ out) {
    __shared__ float red[256];
    float a = 0.f;
    for (int i = threadIdx.x; i < n; i += 256) a += partials[i];
    red[threadIdx.x] = a;
    __syncthreads();
    #pragma unroll
    for (int st = 128; st > 0; st >>= 1) {
        if (threadIdx.x < st) red[threadIdx.x] += red[threadIdx.x + st];
        __syncthreads();
    }
    if (threadIdx.x == 0) out[0] = -red[0];
}

// ---------------------------------------------------------------------------
// Fallback: direct 125-tap (only if ws is tiny).
// ---------------------------------------------------------------------------
__global__ __launch_bounds__(256) void lcc_direct(const float* __restrict__ f,
                                                  const float* __restrict__ m,
                                                  float* __restrict__ partials) {
    float acc = 0.f;
    for (int idx = blockIdx.x * 256 + threadIdx.x; idx < NVOX; idx += 256 * gridDim.x) {
        const int z = idx % DZ;
        const int y = (idx / DZ) % DY;
        const int x = idx / PLANE;
        float sf = 0, sm = 0, sfm = 0, sff = 0, smm = 0;
        for (int dx = -2; dx <= 2; ++dx) {
            const int xx = iclamp(x + dx, DX - 1);
            for (int dy = -2; dy <= 2; ++dy) {
                const int yy = iclamp(y + dy, DY - 1);
                const size_t b = (size_t)xx * PLANE + (size_t)yy * DZ;
                #pragma unroll
                for (int dz = -2; dz <= 2; ++dz) {
                    const int zz = iclamp(z + dz, DZ - 1);
                    const float fv = f[b + zz], mv = m[b + zz];
                    sf += fv; sm += mv; sfm += fv * mv; sff += fv * fv; smm += mv * mv;
                }
            }
        }
        const float inv = 1.0f / 125.0f;
        const float cross = sfm - sf * sm * inv;
        const float fvar  = sff - sf * sf * inv;
        const float mvar  = smm - sm * sm * inv;
        acc += cross * cross / (fvar * mvar + 0.1f);
    }
    __shared__ float red[256];
    red[threadIdx.x] = acc;
    __syncthreads();
    #pragma unroll
    for (int st = 128; st > 0; st >>= 1) {
        if (threadIdx.x < st) red[threadIdx.x] += red[threadIdx.x + st];
        __syncthreads();
    }
    if (threadIdx.x == 0) partials[blockIdx.x] = red[0];
}

extern "C" void kernel_launch(void* const* d_in, const int* in_sizes, int n_in,
                              void* d_out, int out_size, void* d_ws, size_t ws_size,
                              hipStream_t stream) {
    const float* f = (const float*)d_in[0];
    const float* m = (const float*)d_in[1];
    float* out = (float*)d_out;

    if (ws_size >= NPART * sizeof(float)) {
        float* partials = (float*)d_ws;
        lcc_fused<<<dim3(NXB, NBY), NT, 0, stream>>>(f, m, partials);
        lcc_finalize<<<1, 256, 0, stream>>>(partials, NPART, out);
    } else {
        const int nb = 512;
        float* partials = (float*)d_ws;
        lcc_direct<<<nb, 256, 0, stream>>>(f, m, partials);
        lcc_finalize<<<1, 256, 0, stream>>>(partials, nb, out);
    }
}

// Round 20
// 32.789 us; speedup vs baseline: 1.2893x; 1.2893x over previous
//
#include <hip/hip_runtime.h>
#include <hip/hip_fp16.h>

#define DX 160
#define DY 192
#define DZ 160
#define PLANE (DY*DZ)
#define NVOX (DX*DY*DZ)

#define ZP   80            // z-pairs (z = 2*zp, 2*zp+1), full z-line
#define YC   4             // interior y rows per block
#define NYB  (DY/YC)       // 48
#define XC   10            // interior x slices per block
#define NXB  (DX/XC)       // 16
#define NS   (XC+4)        // 14 slices (even: unroll-2 for static buffer parity)
#define ROWS (YC+4)        // 8 slab rows
#define NT   (YC*ZP)       // 320 threads = 5 waves
#define NBLK (NXB*NYB)     // 768 blocks
#define RAWN (ROWS*DZ)     // 1280 floats per volume per buffer = NT float4s

__device__ __forceinline__ int iclamp(int v, int hi) {
    return v < 0 ? 0 : (v > hi ? hi : v);
}
__device__ __forceinline__ __half2 h2(int v) {
    return __builtin_bit_cast(__half2, v);
}

// HW direct global->LDS, 16B per lane. LDS dest must be wave-uniform base +
// lane*16 (our tid*16 layout satisfies it); global source is per-lane.
__device__ __forceinline__ void gld16(const float* g, float* l) {
    __builtin_amdgcn_global_load_lds(
        (const __attribute__((address_space(1))) void*)g,
        (__attribute__((address_space(3))) void*)l, 16, 0, 0);
}

// ---------------------------------------------------------------------------
// Fused LCC, async-staged edition (R10/R11 base = best measured, 28.4us).
// R19 killed the wave-autonomy branch (4 rounds, never < 38us). Residual
// cost in the best structure: staging round-trip global->VGPR->LDS (8 scalar
// loads + 4 ds_write_b64/thread/slice) with vmcnt-coupled writes.
// This round replaces it with global_load_lds width=16 (2 insts/thread/slice,
// zero staging VGPRs) in a depth-2, ONE-barrier-per-slice pipeline:
//   iter i: stage1(buf[i&1]) -> ybuf[i&1]
//           __syncthreads()   (drains loads issued at iter i-1: full-slice
//                              flight time -> latency covered)
//           issue slice i+2 -> buf[i&1]   (readers all passed the barrier)
//           stage2(ybuf[i&1]) + x-window + LCC
// Hazards: buf[p] overwritten only after barrier following its last reader;
// ybuf[p] rewritten at i+2 only after barrier(i+1); loads drained by the
// compiler's vmcnt(0) in every __syncthreads (verified codegen, guide m97).
// ---------------------------------------------------------------------------
__global__ __launch_bounds__(NT, 4) void lcc_fused(const float* __restrict__ F,
                                                   const float* __restrict__ M,
                                                   float* __restrict__ partials) {
    __shared__ float    rawF[2][RAWN];   // 2 x 5120 B
    __shared__ float    rawM[2][RAWN];   // 2 x 5120 B
    __shared__ int4     ybA[2][YC * ZP]; // 2 x 5120 B
    __shared__ unsigned ybB[2][YC * ZP]; // 2 x 1280 B
    __shared__ float    wred[8];         // total ~33.3 KB

    const int tid = threadIdx.x;
    const int zp  = tid % ZP;
    const int ty  = tid / ZP;
    const int y0  = blockIdx.y * YC;
    const int x0  = blockIdx.x * XC;

    // one float4 slot per thread: row = tid/40 (0..7), z = (tid%40)*4
    const int grow = tid / 40;
    const int gz   = (tid % 40) * 4;
    const int soff = iclamp(y0 + grow - 2, DY - 1) * DZ + gz;
    const int ldst = tid * 4;            // float index into rawF/rawM

    auto issue = [&](int j, int buf) {
        const int xx = iclamp(x0 + j - 2, DX - 1);
        gld16(F + (size_t)xx * PLANE + soff, &rawF[buf][ldst]);
        gld16(M + (size_t)xx * PLANE + soff, &rawM[buf][ldst]);
    };

    // ---- prologue: slices 0,1 into buf 0,1 ----
    issue(0, 0);
    issue(1, 1);

    // x running-window state
    float acc = 0.f;
    float sA[5], sB[5];
    unsigned hp[4][5];          // history: half2(SA[q], SB[q]) per step
    #pragma unroll
    for (int q = 0; q < 5; ++q) { sA[q] = 0.f; sB[q] = 0.f; }
    #pragma unroll
    for (int k = 0; k < 4; ++k)
        #pragma unroll
        for (int q = 0; q < 5; ++q) hp[k][q] = 0u;

    __syncthreads();   // drains prologue loads

    auto body = [&](int i, int par) {
        // ---- stage1: y-box (5 row taps) from rawF/rawM[par], f32 exact ----
        float yA[5] = {0,0,0,0,0};  // q: f, m, fm, ff, mm  @ z0
        float yB[5] = {0,0,0,0,0};  //                      @ z1
        #pragma unroll
        for (int k = 0; k < 5; ++k) {
            const float2 tf = *(const float2*)&rawF[par][(ty + k) * DZ + 2 * zp];
            const float2 tm = *(const float2*)&rawM[par][(ty + k) * DZ + 2 * zp];
            yA[0] += tf.x; yA[1] += tm.x;
            yA[2] = fmaf(tf.x, tm.x, yA[2]);
            yA[3] = fmaf(tf.x, tf.x, yA[3]);
            yA[4] = fmaf(tm.x, tm.x, yA[4]);
            yB[0] += tf.y; yB[1] += tm.y;
            yB[2] = fmaf(tf.y, tm.y, yB[2]);
            yB[3] = fmaf(tf.y, tf.y, yB[3]);
            yB[4] = fmaf(tm.y, tm.y, yB[4]);
        }
        // ---- pack Y -> fp16 ybuf[par] ----
        int4 w;
        w.x = __builtin_bit_cast(int, __floats2half2_rn(yA[0], yA[1]));
        w.y = __builtin_bit_cast(int, __floats2half2_rn(yA[2], yA[3]));
        w.z = __builtin_bit_cast(int, __floats2half2_rn(yB[0], yB[1]));
        w.w = __builtin_bit_cast(int, __floats2half2_rn(yB[2], yB[3]));
        ybA[par][ty * ZP + zp] = w;
        ybB[par][ty * ZP + zp] = __builtin_bit_cast(unsigned, __floats2half2_rn(yA[4], yB[4]));

        __syncthreads();   // ybuf[par] visible; loads for slice i+1 drained;
                           // all stage1 readers of rawS[par] are past here.

        // ---- issue async loads slice i+2 -> buf[par] (full-slice flight) ----
        if (i + 2 < NS) issue(i + 2, par);

        // ---- stage2: z-box over pairs from ybuf[par] (taps z0-2 .. z0+3) ----
        const int base = ty * ZP;
        int4 p0 = ybA[par][base + (zp == 0      ? 0      : zp - 1)];
        int4 p1 = ybA[par][base + zp];
        int4 p2 = ybA[par][base + (zp == ZP - 1 ? ZP - 1 : zp + 1)];
        unsigned b0 = ybB[par][base + (zp == 0      ? 0      : zp - 1)];
        unsigned b2 = ybB[par][base + (zp == ZP - 1 ? ZP - 1 : zp + 1)];
        const unsigned b1 = ybB[par][base + zp];
        if (zp == 0)      { p0.z = p0.x; p0.w = p0.y; b0 = (b0 & 0xffffu) | (b0 << 16); }
        if (zp == ZP - 1) { p2.x = p2.z; p2.y = p2.w; b2 = (b2 >> 16) | (b2 & 0xffff0000u); }

        const __half2 t0  = __hadd2(__hadd2(h2(p0.z), h2(p1.x)), __hadd2(h2(p1.z), h2(p2.x)));
        const __half2 A01 = __hadd2(t0, h2(p0.x));
        const __half2 B01 = __hadd2(t0, h2(p2.z));
        const __half2 t1  = __hadd2(__hadd2(h2(p0.w), h2(p1.y)), __hadd2(h2(p1.w), h2(p2.y)));
        const __half2 A23 = __hadd2(t1, h2(p0.y));
        const __half2 B23 = __hadd2(t1, h2(p2.w));
        const __half2 c0 = h2((int)b0), c1 = h2((int)b1), c2 = h2((int)b2);
        const float tb = __high2float(c0) + __low2float(c1) + __high2float(c1) + __low2float(c2);
        const float SA[5] = { __low2float(A01), __high2float(A01),
                              __low2float(A23), __high2float(A23),
                              tb + __low2float(c0) };
        const float SB[5] = { __low2float(B01), __high2float(B01),
                              __low2float(B23), __high2float(B23),
                              tb + __high2float(c2) };

        // ---- x running window + LCC ----
        #pragma unroll
        for (int q = 0; q < 5; ++q) { sA[q] += SA[q]; sB[q] += SB[q]; }
        if (i >= 4) {
            const float inv = 1.0f / 125.0f;
            {
                const float cross = sA[2] - sA[0] * sA[1] * inv;
                const float fvar  = sA[3] - sA[0] * sA[0] * inv;
                const float mvar  = sA[4] - sA[1] * sA[1] * inv;
                acc += cross * cross / (fvar * mvar + 0.1f);
            }
            {
                const float cross = sB[2] - sB[0] * sB[1] * inv;
                const float fvar  = sB[3] - sB[0] * sB[0] * inv;
                const float mvar  = sB[4] - sB[1] * sB[1] * inv;
                acc += cross * cross / (fvar * mvar + 0.1f);
            }
            #pragma unroll
            for (int q = 0; q < 5; ++q) {
                const __half2 v = h2((int)hp[0][q]);
                sA[q] -= __low2float(v);
                sB[q] -= __high2float(v);
            }
        }
        #pragma unroll
        for (int k = 0; k < 3; ++k)
            #pragma unroll
            for (int q = 0; q < 5; ++q) hp[k][q] = hp[k + 1][q];
        #pragma unroll
        for (int q = 0; q < 5; ++q)
            hp[3][q] = __builtin_bit_cast(unsigned, __floats2half2_rn(SA[q], SB[q]));
    };

    // slice i lives in buf[i&1]; NS=14 even -> 7 unrolled pairs, static parity
    #pragma unroll
    for (int ib = 0; ib < NS; ib += 2) {
        body(ib,     0);
        body(ib + 1, 1);
    }

    // ---- reduction: wave shuffle (no barrier) + tiny LDS combine ----
    #pragma unroll
    for (int off = 32; off > 0; off >>= 1) acc += __shfl_down(acc, off, 64);
    if ((tid & 63) == 0) wred[tid >> 6] = acc;
    __syncthreads();
    if (tid == 0) {
        float a = 0.f;
        #pragma unroll
        for (int wv = 0; wv < NT / 64; ++wv) a += wred[wv];
        partials[blockIdx.y * NXB + blockIdx.x] = a;
    }
}

// ---------------------------------------------------------------------------
// Final deterministic reduction, writes -sum.
// ---------------------------------------------------------------------------
__global__ __launch_bounds__(256) void lcc_finalize(const float* __restrict__ partials,
                                                    int n, float* __restrict__ out) {
    __shared__ float red[256];
    float a = 0.f;
    for (int i = threadIdx.x; i < n; i += 256) a += partials[i];
    red[threadIdx.x] = a;
    __syncthreads();
    #pragma unroll
    for (int st = 128; st > 0; st >>= 1) {
        if (threadIdx.x < st) red[threadIdx.x] += red[threadIdx.x + st];
        __syncthreads();
    }
    if (threadIdx.x == 0) out[0] = -red[0];
}

// ---------------------------------------------------------------------------
// Fallback: direct 125-tap (only if ws is tiny).
// ---------------------------------------------------------------------------
__global__ __launch_bounds__(256) void lcc_direct(const float* __restrict__ f,
                                                  const float* __restrict__ m,
                                                  float* __restrict__ partials) {
    float acc = 0.f;
    for (int idx = blockIdx.x * 256 + threadIdx.x; idx < NVOX; idx += 256 * gridDim.x) {
        const int z = idx % DZ;
        const int y = (idx / DZ) % DY;
        const int x = idx / PLANE;
        float sf = 0, sm = 0, sfm = 0, sff = 0, smm = 0;
        for (int dx = -2; dx <= 2; ++dx) {
            const int xx = iclamp(x + dx, DX - 1);
            for (int dy = -2; dy <= 2; ++dy) {
                const int yy = iclamp(y + dy, DY - 1);
                const size_t b = (size_t)xx * PLANE + (size_t)yy * DZ;
                #pragma unroll
                for (int dz = -2; dz <= 2; ++dz) {
                    const int zz = iclamp(z + dz, DZ - 1);
                    const float fv = f[b + zz], mv = m[b + zz];
                    sf += fv; sm += mv; sfm += fv * mv; sff += fv * fv; smm += mv * mv;
                }
            }
        }
        const float inv = 1.0f / 125.0f;
        const float cross = sfm - sf * sm * inv;
        const float fvar  = sff - sf * sf * inv;
        const float mvar  = smm - sm * sm * inv;
        acc += cross * cross / (fvar * mvar + 0.1f);
    }
    __shared__ float red[256];
    red[threadIdx.x] = acc;
    __syncthreads();
    #pragma unroll
    for (int st = 128; st > 0; st >>= 1) {
        if (threadIdx.x < st) red[threadIdx.x] += red[threadIdx.x + st];
        __syncthreads();
    }
    if (threadIdx.x == 0) partials[blockIdx.x] = red[0];
}

extern "C" void kernel_launch(void* const* d_in, const int* in_sizes, int n_in,
                              void* d_out, int out_size, void* d_ws, size_t ws_size,
                              hipStream_t stream) {
    const float* f = (const float*)d_in[0];
    const float* m = (const float*)d_in[1];
    float* out = (float*)d_out;

    if (ws_size >= NBLK * sizeof(float)) {
        float* partials = (float*)d_ws;
        lcc_fused<<<dim3(NXB, NYB), NT, 0, stream>>>(f, m, partials);
        lcc_finalize<<<1, 256, 0, stream>>>(partials, NBLK, out);
    } else {
        const int nb = 512;
        float* partials = (float*)d_ws;
        lcc_direct<<<nb, 256, 0, stream>>>(f, m, partials);
        lcc_finalize<<<1, 256, 0, stream>>>(partials, nb, out);
    }
}

// Round 21
// 31.950 us; speedup vs baseline: 1.3232x; 1.0263x over previous
//
#include <hip/hip_runtime.h>
#include <hip/hip_fp16.h>

#define DX 160
#define DY 192
#define DZ 160
#define PLANE (DY*DZ)
#define NVOX (DX*DY*DZ)

#define ZP   80            // z-pairs (z = 2*zp, 2*zp+1), full z-line
#define YC   4             // interior y rows per block
#define NYB  (DY/YC)       // 48
#define XC   10            // interior x slices per block
#define NXB  (DX/XC)       // 16
#define NS   (XC+4)        // 14 slices per block (even: 7 pair-iterations)
#define NPAIR (NS/2)       // 7
#define ROWS (YC+4)        // 8 slab rows
#define NT   (YC*ZP)       // 320 threads = 5 waves
#define NBLK (NXB*NYB)     // 768 blocks

__device__ __forceinline__ int iclamp(int v, int hi) {
    return v < 0 ? 0 : (v > hi ? hi : v);
}

__device__ __forceinline__ __half2 h2(int v) {
    return __builtin_bit_cast(__half2, v);
}

// ---------------------------------------------------------------------------
// Fused LCC = R11 (best measured, 28.4us: slice-paired, dual LDS buffers,
// register prefetch, 1 barrier/slice-pair boundary) with ONE change:
// x-window history kept in plain f32 registers instead of fp16-packed words.
// R4's fp16 packing dodged a 960-thread spill that no longer applies (320-
// thread blocks get ~84+ VGPRs, R6/R8); the pack/unpack cvts (~15 VALU +
// 2 cvt-latency hops per slice) sat on the serial window-update chain.
// Single-variable experiment: if WRITE_SIZE stays ~0 (no spill) and time
// drops, cvt latency was part of the 75% issue-stall; if it spills or is
// neutral, the structure is at its practical plateau.
// ---------------------------------------------------------------------------
__global__ __launch_bounds__(NT, 2) void lcc_fused(const float* __restrict__ F,
                                                   const float* __restrict__ M,
                                                   float* __restrict__ partials) {
    __shared__ float4   rawS[2][ROWS * ZP];  // 2 x 10240 B
    __shared__ int4     ybA[2][YC * ZP];     // 2 x  5120 B
    __shared__ unsigned ybB[2][YC * ZP];     // 2 x  1280 B
    __shared__ float    wred[8];             // total ~35.3 KB

    const int tid = threadIdx.x;
    const int zp  = tid % ZP;
    const int ty  = tid / ZP;
    const int y0  = blockIdx.y * YC;
    const int x0  = blockIdx.x * XC;

    // hoisted staging offsets (4 float2 slots per thread, exact cover)
    int soff[4];
    #pragma unroll
    for (int k = 0; k < 4; ++k) {
        const int e   = tid + k * NT;
        const int row = e / DZ, zz = e % DZ;
        soff[k] = iclamp(y0 + row - 2, DY - 1) * DZ + zz;
    }

    auto issueR = [&](int j, float (&pf)[4], float (&pm)[4]) {
        const int xx = iclamp(x0 + j - 2, DX - 1);
        const float* fp = F + (size_t)xx * PLANE;
        const float* mp = M + (size_t)xx * PLANE;
        #pragma unroll
        for (int k = 0; k < 4; ++k) { pf[k] = fp[soff[k]]; pm[k] = mp[soff[k]]; }
    };
    auto writeW = [&](int buf, const float (&pf)[4], const float (&pm)[4]) {
        #pragma unroll
        for (int k = 0; k < 4; ++k)
            ((float2*)rawS[buf])[tid + k * NT] = make_float2(pf[k], pm[k]);
    };
    auto stage1 = [&](int buf) {   // reads rawS[buf], writes ybuf[buf]
        float yA[5] = {0,0,0,0,0};
        float yB[5] = {0,0,0,0,0};
        #pragma unroll
        for (int k = 0; k < 5; ++k) {
            const float4 t = rawS[buf][(ty + k) * ZP + zp];
            yA[0] += t.x; yA[1] += t.y;
            yA[2] = fmaf(t.x, t.y, yA[2]);
            yA[3] = fmaf(t.x, t.x, yA[3]);
            yA[4] = fmaf(t.y, t.y, yA[4]);
            yB[0] += t.z; yB[1] += t.w;
            yB[2] = fmaf(t.z, t.w, yB[2]);
            yB[3] = fmaf(t.z, t.z, yB[3]);
            yB[4] = fmaf(t.w, t.w, yB[4]);
        }
        int4 w;
        w.x = __builtin_bit_cast(int, __floats2half2_rn(yA[0], yA[1]));
        w.y = __builtin_bit_cast(int, __floats2half2_rn(yA[2], yA[3]));
        w.z = __builtin_bit_cast(int, __floats2half2_rn(yB[0], yB[1]));
        w.w = __builtin_bit_cast(int, __floats2half2_rn(yB[2], yB[3]));
        ybA[buf][ty * ZP + zp] = w;
        ybB[buf][ty * ZP + zp] = __builtin_bit_cast(unsigned, __floats2half2_rn(yA[4], yB[4]));
    };

    // ---- x-window state: running sums + f32 history (the experiment) ----
    float acc = 0.f;
    float sA[5], sB[5];
    float hA[4][5], hB[4][5];
    #pragma unroll
    for (int q = 0; q < 5; ++q) { sA[q] = 0.f; sB[q] = 0.f; }
    #pragma unroll
    for (int k = 0; k < 4; ++k)
        #pragma unroll
        for (int q = 0; q < 5; ++q) { hA[k][q] = 0.f; hB[k][q] = 0.f; }

    auto s2win = [&](int buf, int i) {   // stage2 z-box from ybuf[buf] + x-window
        const int base = ty * ZP;
        int4 p0 = ybA[buf][base + (zp == 0      ? 0      : zp - 1)];
        int4 p1 = ybA[buf][base + zp];
        int4 p2 = ybA[buf][base + (zp == ZP - 1 ? ZP - 1 : zp + 1)];
        unsigned b0 = ybB[buf][base + (zp == 0      ? 0      : zp - 1)];
        unsigned b2 = ybB[buf][base + (zp == ZP - 1 ? ZP - 1 : zp + 1)];
        const unsigned b1 = ybB[buf][base + zp];
        if (zp == 0)      { p0.z = p0.x; p0.w = p0.y; b0 = (b0 & 0xffffu) | (b0 << 16); }
        if (zp == ZP - 1) { p2.x = p2.z; p2.y = p2.w; b2 = (b2 >> 16) | (b2 & 0xffff0000u); }

        const __half2 t0  = __hadd2(__hadd2(h2(p0.z), h2(p1.x)), __hadd2(h2(p1.z), h2(p2.x)));
        const __half2 A01 = __hadd2(t0, h2(p0.x));
        const __half2 B01 = __hadd2(t0, h2(p2.z));
        const __half2 t1  = __hadd2(__hadd2(h2(p0.w), h2(p1.y)), __hadd2(h2(p1.w), h2(p2.y)));
        const __half2 A23 = __hadd2(t1, h2(p0.y));
        const __half2 B23 = __hadd2(t1, h2(p2.w));
        const __half2 c0 = h2((int)b0), c1 = h2((int)b1), c2 = h2((int)b2);
        const float tb = __high2float(c0) + __low2float(c1) + __high2float(c1) + __low2float(c2);
        const float SA[5] = { __low2float(A01), __high2float(A01),
                              __low2float(A23), __high2float(A23),
                              tb + __low2float(c0) };
        const float SB[5] = { __low2float(B01), __high2float(B01),
                              __low2float(B23), __high2float(B23),
                              tb + __high2float(c2) };

        #pragma unroll
        for (int q = 0; q < 5; ++q) { sA[q] += SA[q]; sB[q] += SB[q]; }
        if (i >= 4) {
            const float inv = 1.0f / 125.0f;
            {
                const float cross = sA[2] - sA[0] * sA[1] * inv;
                const float fvar  = sA[3] - sA[0] * sA[0] * inv;
                const float mvar  = sA[4] - sA[1] * sA[1] * inv;
                acc += cross * cross / (fvar * mvar + 0.1f);
            }
            {
                const float cross = sB[2] - sB[0] * sB[1] * inv;
                const float fvar  = sB[3] - sB[0] * sB[0] * inv;
                const float mvar  = sB[4] - sB[1] * sB[1] * inv;
                acc += cross * cross / (fvar * mvar + 0.1f);
            }
            #pragma unroll
            for (int q = 0; q < 5; ++q) { sA[q] -= hA[0][q]; sB[q] -= hB[0][q]; }
        }
        #pragma unroll
        for (int k = 0; k < 3; ++k)
            #pragma unroll
            for (int q = 0; q < 5; ++q) { hA[k][q] = hA[k + 1][q]; hB[k][q] = hB[k + 1][q]; }
        #pragma unroll
        for (int q = 0; q < 5; ++q) { hA[3][q] = SA[q]; hB[3][q] = SB[q]; }
    };

    // ---- prologue: slices 0,1 ----
    float pfA[4], pmA[4], pfB[4], pmB[4];
    issueR(0, pfA, pmA);
    issueR(1, pfB, pmB);
    writeW(0, pfA, pmA);
    writeW(1, pfB, pmB);
    __syncthreads();

    // ---- paired main loop: iteration t = slices (2t, 2t+1) ----
    for (int t = 0; t < NPAIR; ++t) {
        const int s0 = 2 * t;
        if (t + 1 < NPAIR) {               // prefetch next pair (full-region cover)
            issueR(s0 + 2, pfA, pmA);
            issueR(s0 + 3, pfB, pmB);
        }
        stage1(0);                          // slice s0   (independent chains,
        stage1(1);                          // slice s0+1  compiler interleaves)
        __syncthreads();                    // ybuf[0..1] visible; rawS reads done
        s2win(0, s0);
        s2win(1, s0 + 1);
        if (t + 1 < NPAIR) {
            writeW(0, pfA, pmA);            // rawS readers passed barrier above
            writeW(1, pfB, pmB);
            __syncthreads();                // rawS ready; ybuf reads done
        }
    }

    // ---- reduction: wave shuffle (no barrier) + tiny LDS combine ----
    #pragma unroll
    for (int off = 32; off > 0; off >>= 1) acc += __shfl_down(acc, off, 64);
    if ((tid & 63) == 0) wred[tid >> 6] = acc;
    __syncthreads();
    if (tid == 0) {
        float a = 0.f;
        #pragma unroll
        for (int w = 0; w < NT / 64; ++w) a += wred[w];
        partials[blockIdx.y * NXB + blockIdx.x] = a;
    }
}

// ---------------------------------------------------------------------------
// Final deterministic reduction, writes -sum.
// ---------------------------------------------------------------------------
__global__ __launch_bounds__(256) void lcc_finalize(const float* __restrict__ partials,
                                                    int n, float* __restrict__ out) {
    __shared__ float red[256];
    float a = 0.f;
    for (int i = threadIdx.x; i < n; i += 256) a += partials[i];
    red[threadIdx.x] = a;
    __syncthreads();
    #pragma unroll
    for (int st = 128; st > 0; st >>= 1) {
        if (threadIdx.x < st) red[threadIdx.x] += red[threadIdx.x + st];
        __syncthreads();
    }
    if (threadIdx.x == 0) out[0] = -red[0];
}

// ---------------------------------------------------------------------------
// Fallback: direct 125-tap (only if ws is tiny).
// ---------------------------------------------------------------------------
__global__ __launch_bounds__(256) void lcc_direct(const float* __restrict__ f,
                                                  const float* __restrict__ m,
                                                  float* __restrict__ partials) {
    float acc = 0.f;
    for (int idx = blockIdx.x * 256 + threadIdx.x; idx < NVOX; idx += 256 * gridDim.x) {
        const int z = idx % DZ;
        const int y = (idx / DZ) % DY;
        const int x = idx / PLANE;
        float sf = 0, sm = 0, sfm = 0, sff = 0, smm = 0;
        for (int dx = -2; dx <= 2; ++dx) {
            const int xx = iclamp(x + dx, DX - 1);
            for (int dy = -2; dy <= 2; ++dy) {
                const int yy = iclamp(y + dy, DY - 1);
                const size_t b = (size_t)xx * PLANE + (size_t)yy * DZ;
                #pragma unroll
                for (int dz = -2; dz <= 2; ++dz) {
                    const int zz = iclamp(z + dz, DZ - 1);
                    const float fv = f[b + zz], mv = m[b + zz];
                    sf += fv; sm += mv; sfm += fv * mv; sff += fv * fv; smm += mv * mv;
                }
            }
        }
        const float inv = 1.0f / 125.0f;
        const float cross = sfm - sf * sm * inv;
        const float fvar  = sff - sf * sf * inv;
        const float mvar  = smm - sm * sm * inv;
        acc += cross * cross / (fvar * mvar + 0.1f);
    }
    __shared__ float red[256];
    red[threadIdx.x] = acc;
    __syncthreads();
    #pragma unroll
    for (int st = 128; st > 0; st >>= 1) {
        if (threadIdx.x < st) red[threadIdx.x] += red[threadIdx.x + st];
        __syncthreads();
    }
    if (threadIdx.x == 0) partials[blockIdx.x] = red[0];
}

extern "C" void kernel_launch(void* const* d_in, const int* in_sizes, int n_in,
                              void* d_out, int out_size, void* d_ws, size_t ws_size,
                              hipStream_t stream) {
    const float* f = (const float*)d_in[0];
    const float* m = (const float*)d_in[1];
    float* out = (float*)d_out;

    if (ws_size >= NBLK * sizeof(float)) {
        float* partials = (float*)d_ws;
        lcc_fused<<<dim3(NXB, NYB), NT, 0, stream>>>(f, m, partials);
        lcc_finalize<<<1, 256, 0, stream>>>(partials, NBLK, out);
    } else {
        const int nb = 512;
        float* partials = (float*)d_ws;
        lcc_direct<<<nb, 256, 0, stream>>>(f, m, partials);
        lcc_finalize<<<1, 256, 0, stream>>>(partials, nb, out);
    }
}